// Round 2
// baseline (370.144 us; speedup 1.0000x reference)
//
#include <hip/hip_runtime.h>

// Problem constants (from reference)
#define BB 16
#define HH 299
#define WW 299
#define KK 8
#define HWPIX (HH * WW)          // 89401
#define NPIX (BB * HWPIX)        // 1430416
#define GPB (HWPIX / 4)          // 22350 full 4-pixel groups per batch
#define NGROUPS (BB * GPB)       // 357600
#define NTHREADS (NGROUPS + BB)  // 357616 (one tail pixel per batch: rem=89400)
#define TPB 256

typedef float f4 __attribute__((ext_vector_type(4)));
// Planar rows have odd stride (89401 floats) -> 4-byte-aligned wide stores.
typedef f4 uf4 __attribute__((aligned(4)));

// 56-VGPR baseline proved register budget was never binding; keep cap at 128
// (4 waves/SIMD) so the 32 gather destinations can stay live.
__global__ __launch_bounds__(TPB, 4) void gauss_net_kernel(
    const f4* __restrict__ spatial,  // (N_POINTS, 4)
    const f4* __restrict__ wi4,      // (B, 2, H, W, K) viewed as f4
    const f4* __restrict__ ori,      // (B, H, W, 4)
    float* __restrict__ out)
{
    const int gid = blockIdx.x * TPB + threadIdx.x;
    if (gid >= NTHREADS) return;

    // Output layout (flat float offsets)
    f4*    out_x    = (f4*)out;
    f4*    out_rgba = out_x + NPIX;
    float* out_cla  = (float*)(out_rgba + NPIX);
    f4*    out_ori  = (f4*)(out_cla + (size_t)BB * 3 * HWPIX);
    float* out_ocla = (float*)(out_ori + NPIX);

    if (gid < NGROUPS) {
        // ---- full 4-consecutive-pixel group, single batch b ----
        const int b   = gid / GPB;
        const int rem = (gid - b * GPB) * 4;          // multiple of 4
        const size_t p  = (size_t)b * HWPIX + rem;    // flat pixel index
        const size_t wb = ((size_t)(2 * b) * HWPIX + rem) * 2;  // f4 units
        const size_t ib = wb + (size_t)2 * HWPIX;

        // Phase 1: streaming loads (read-once -> nt)
        f4 w[4][2], iv[4][2], o[4];
#pragma unroll
        for (int j = 0; j < 4; ++j) {
            w[j][0]  = __builtin_nontemporal_load(wi4 + wb + 2 * j);
            w[j][1]  = __builtin_nontemporal_load(wi4 + wb + 2 * j + 1);
            iv[j][0] = __builtin_nontemporal_load(wi4 + ib + 2 * j);
            iv[j][1] = __builtin_nontemporal_load(wi4 + ib + 2 * j + 1);
            o[j]     = __builtin_nontemporal_load(ori + p + j);
        }

        // Phase 2: issue all 32 gathers before consuming any
        f4 g[4][KK];
#pragma unroll
        for (int j = 0; j < 4; ++j) {
            int id[KK] = { (int)iv[j][0].x, (int)iv[j][0].y, (int)iv[j][0].z, (int)iv[j][0].w,
                           (int)iv[j][1].x, (int)iv[j][1].y, (int)iv[j][1].z, (int)iv[j][1].w };
#pragma unroll
            for (int k = 0; k < KK; ++k) g[j][k] = spatial[id[k]];
        }

        // Phase 3: reduce + epilogue; per-pixel f4 stores
        float cr[4], cg[4], cb[4], ca[4];
        float or_[4], og_[4], ob_[4];
        bool  oa[4];
#pragma unroll
        for (int j = 0; j < 4; ++j) {
            float wt[KK] = { w[j][0].x, w[j][0].y, w[j][0].z, w[j][0].w,
                             w[j][1].x, w[j][1].y, w[j][1].z, w[j][1].w };
            f4 acc = (f4){0.f, 0.f, 0.f, 0.f};
#pragma unroll
            for (int k = 0; k < KK; ++k) acc += g[j][k] * wt[k];

            f4 ov = o[j];
            float alpha = acc.w * (1.0f / 255.0f);
            float r  = fmaf(acc.x, alpha, ov.x);
            float gr = fmaf(acc.y, alpha, ov.y);
            float bl = fmaf(acc.z, alpha, ov.z);
            oa[j] = (ov.w > 0.0f);
            if (!oa[j]) { r = 0.f; gr = 0.f; bl = 0.f; }

            cr[j] = fminf(fmaxf(r,  0.f), 255.f);
            cg[j] = fminf(fmaxf(gr, 0.f), 255.f);
            cb[j] = fminf(fmaxf(bl, 0.f), 255.f);
            ca[j] = fminf(fmaxf(ov.w, 0.f), 255.f);
            or_[j] = ov.x; og_[j] = ov.y; ob_[j] = ov.z;

            __builtin_nontemporal_store(acc, out_x + p + j);
            __builtin_nontemporal_store((f4){cr[j], cg[j], cb[j], ca[j]}, out_rgba + p + j);
            __builtin_nontemporal_store(ov, out_ori + p + j);
        }

        // Planar stores: one f4 per plane per group (was 4 scalars each).
        // ca[j] > 0  <=>  ov.w > 0  == oa[j]  (clamp preserves sign)
        const size_t cbase = (size_t)b * 3 * HWPIX + rem;
        f4 vcr = { oa[0] ? cr[0] : 255.f, oa[1] ? cr[1] : 255.f,
                   oa[2] ? cr[2] : 255.f, oa[3] ? cr[3] : 255.f };
        f4 vcg = { oa[0] ? cg[0] : 255.f, oa[1] ? cg[1] : 255.f,
                   oa[2] ? cg[2] : 255.f, oa[3] ? cg[3] : 255.f };
        f4 vcb = { oa[0] ? cb[0] : 255.f, oa[1] ? cb[1] : 255.f,
                   oa[2] ? cb[2] : 255.f, oa[3] ? cb[3] : 255.f };
        __builtin_nontemporal_store(vcr, (uf4*)(out_cla + cbase));
        __builtin_nontemporal_store(vcg, (uf4*)(out_cla + cbase + HWPIX));
        __builtin_nontemporal_store(vcb, (uf4*)(out_cla + cbase + 2 * (size_t)HWPIX));

        f4 vor = { oa[0] ? or_[0] : 255.f, oa[1] ? or_[1] : 255.f,
                   oa[2] ? or_[2] : 255.f, oa[3] ? or_[3] : 255.f };
        f4 vog = { oa[0] ? og_[0] : 255.f, oa[1] ? og_[1] : 255.f,
                   oa[2] ? og_[2] : 255.f, oa[3] ? og_[3] : 255.f };
        f4 vob = { oa[0] ? ob_[0] : 255.f, oa[1] ? ob_[1] : 255.f,
                   oa[2] ? ob_[2] : 255.f, oa[3] ? ob_[3] : 255.f };
        __builtin_nontemporal_store(vor, (uf4*)(out_ocla + cbase));
        __builtin_nontemporal_store(vog, (uf4*)(out_ocla + cbase + HWPIX));
        __builtin_nontemporal_store(vob, (uf4*)(out_ocla + cbase + 2 * (size_t)HWPIX));
    } else {
        // ---- tail: one pixel per batch at rem = HWPIX-1 (16 threads total) ----
        const int b   = gid - NGROUPS;
        const int rem = HWPIX - 1;
        const size_t p  = (size_t)b * HWPIX + rem;
        const size_t wb = ((size_t)(2 * b) * HWPIX + rem) * 2;
        const size_t ib = wb + (size_t)2 * HWPIX;

        f4 w0 = __builtin_nontemporal_load(wi4 + wb);
        f4 w1 = __builtin_nontemporal_load(wi4 + wb + 1);
        f4 i0 = __builtin_nontemporal_load(wi4 + ib);
        f4 i1 = __builtin_nontemporal_load(wi4 + ib + 1);
        f4 ov = __builtin_nontemporal_load(ori + p);

        int id[KK] = { (int)i0.x, (int)i0.y, (int)i0.z, (int)i0.w,
                       (int)i1.x, (int)i1.y, (int)i1.z, (int)i1.w };
        f4 g[KK];
#pragma unroll
        for (int k = 0; k < KK; ++k) g[k] = spatial[id[k]];

        float wt[KK] = { w0.x, w0.y, w0.z, w0.w, w1.x, w1.y, w1.z, w1.w };
        f4 acc = (f4){0.f, 0.f, 0.f, 0.f};
#pragma unroll
        for (int k = 0; k < KK; ++k) acc += g[k] * wt[k];

        float alpha = acc.w * (1.0f / 255.0f);
        float r  = fmaf(acc.x, alpha, ov.x);
        float gr = fmaf(acc.y, alpha, ov.y);
        float bl = fmaf(acc.z, alpha, ov.z);
        bool oa_pos = (ov.w > 0.0f);
        if (!oa_pos) { r = 0.f; gr = 0.f; bl = 0.f; }

        float cr = fminf(fmaxf(r,  0.f), 255.f);
        float cg = fminf(fmaxf(gr, 0.f), 255.f);
        float cb = fminf(fmaxf(bl, 0.f), 255.f);
        float ca = fminf(fmaxf(ov.w, 0.f), 255.f);

        __builtin_nontemporal_store(acc, out_x + p);
        __builtin_nontemporal_store((f4){cr, cg, cb, ca}, out_rgba + p);
        __builtin_nontemporal_store(ov, out_ori + p);

        const size_t cbase = (size_t)b * 3 * HWPIX + rem;
        bool ca_pos = (ca > 0.0f);
        __builtin_nontemporal_store(ca_pos ? cr : 255.0f, out_cla + cbase);
        __builtin_nontemporal_store(ca_pos ? cg : 255.0f, out_cla + cbase + HWPIX);
        __builtin_nontemporal_store(ca_pos ? cb : 255.0f, out_cla + cbase + 2 * (size_t)HWPIX);

        __builtin_nontemporal_store(oa_pos ? ov.x : 255.0f, out_ocla + cbase);
        __builtin_nontemporal_store(oa_pos ? ov.y : 255.0f, out_ocla + cbase + HWPIX);
        __builtin_nontemporal_store(oa_pos ? ov.z : 255.0f, out_ocla + cbase + 2 * (size_t)HWPIX);
    }
}

extern "C" void kernel_launch(void* const* d_in, const int* in_sizes, int n_in,
                              void* d_out, int out_size, void* d_ws, size_t ws_size,
                              hipStream_t stream) {
    const f4* spatial = (const f4*)d_in[0];
    const f4* wi4     = (const f4*)d_in[1];
    const f4* ori     = (const f4*)d_in[2];
    float* out = (float*)d_out;

    int blocks = (NTHREADS + TPB - 1) / TPB;
    gauss_net_kernel<<<blocks, TPB, 0, stream>>>(spatial, wi4, ori, out);
}

// Round 3
// 234.138 us; speedup vs baseline: 1.5809x; 1.5809x over previous
//
#include <hip/hip_runtime.h>

// Problem constants (from reference)
#define BB 16
#define HH 299
#define WW 299
#define KK 8
#define HWPIX (HH * WW)        // 89401
#define NPIX (BB * HWPIX)      // 1430416
#define PPT 4                  // pixels per thread -> 32 gathers in flight
#define TPB 256
#define SPAN (TPB * PPT)

typedef float f4 __attribute__((ext_vector_type(4)));

// __launch_bounds__(256, 2): 256-VGPR budget so all 32 gather destinations
// (128 VGPRs) stay live simultaneously. r1 showed the compiler's default
// choice (56 VGPR, ~9-deep issue window) leaves gathers serialized; this
// round discriminates outstanding-limited vs per-CU-throughput-limited.
__global__ __launch_bounds__(TPB, 2) void gauss_net_kernel(
    const f4* __restrict__ spatial,  // (N_POINTS, 4)
    const f4* __restrict__ wi4,      // (B, 2, H, W, K) viewed as f4
    const f4* __restrict__ ori,      // (B, H, W, 4)
    float* __restrict__ out)
{
    const int tbase = blockIdx.x * SPAN + threadIdx.x;

    // Output layout (flat float offsets)
    f4*    out_x    = (f4*)out;
    f4*    out_rgba = out_x + NPIX;
    float* out_cla  = (float*)(out_rgba + NPIX);
    f4*    out_ori  = (f4*)(out_cla + (size_t)BB * 3 * HWPIX);
    float* out_ocla = (float*)(out_ori + NPIX);

    int  p[PPT], bidx[PPT], rem[PPT];
    bool act[PPT];
    f4   w0[PPT], w1[PPT], o[PPT];
    int  id[PPT][KK];

    // Phase 1: issue ALL streaming loads (weights, indices, ori) — nt, read-once.
    // Lane-consecutive addressing per instruction (coalesced): p = tbase + u*TPB.
#pragma unroll
    for (int u = 0; u < PPT; ++u) {
        p[u]   = tbase + u * TPB;
        act[u] = (p[u] < NPIX);
        int pc = act[u] ? p[u] : 0;
        bidx[u] = pc / HWPIX;
        rem[u]  = pc - bidx[u] * HWPIX;
        size_t wb = ((size_t)(2 * bidx[u]) * HWPIX + rem[u]) * 2;  // f4 units
        size_t ib = wb + (size_t)HWPIX * 2;
        w0[u] = __builtin_nontemporal_load(wi4 + wb);
        w1[u] = __builtin_nontemporal_load(wi4 + wb + 1);
        f4 i0 = __builtin_nontemporal_load(wi4 + ib);
        f4 i1 = __builtin_nontemporal_load(wi4 + ib + 1);
        o[u]  = __builtin_nontemporal_load(ori + pc);
        id[u][0] = (int)i0.x; id[u][1] = (int)i0.y;
        id[u][2] = (int)i0.z; id[u][3] = (int)i0.w;
        id[u][4] = (int)i1.x; id[u][5] = (int)i1.y;
        id[u][6] = (int)i1.z; id[u][7] = (int)i1.w;
    }

    // Phase 2: issue ALL 32 gathers before consuming any.
    f4 g[PPT][KK];
#pragma unroll
    for (int u = 0; u < PPT; ++u)
#pragma unroll
        for (int k = 0; k < KK; ++k) g[u][k] = spatial[id[u][k]];

    // Hard fence: no instruction may cross — the scheduler cannot sink
    // pixel u+1's gathers below pixel u's consumption, so all 32 loads
    // are outstanding simultaneously.
    __builtin_amdgcn_sched_barrier(0);

    // Phase 3: reduce + epilogue + nt stores (r1-identical math/order)
#pragma unroll
    for (int u = 0; u < PPT; ++u) {
        if (!act[u]) continue;
        float wt[KK] = { w0[u].x, w0[u].y, w0[u].z, w0[u].w,
                         w1[u].x, w1[u].y, w1[u].z, w1[u].w };
        f4 acc = (f4){0.f, 0.f, 0.f, 0.f};
#pragma unroll
        for (int k = 0; k < KK; ++k) acc += g[u][k] * wt[k];

        f4 ov = o[u];
        float alpha = acc.w * (1.0f / 255.0f);
        float r  = fmaf(acc.x, alpha, ov.x);
        float gr = fmaf(acc.y, alpha, ov.y);
        float bl = fmaf(acc.z, alpha, ov.z);
        bool oa_pos = (ov.w > 0.0f);
        if (!oa_pos) { r = 0.f; gr = 0.f; bl = 0.f; }

        float cr = fminf(fmaxf(r,  0.f), 255.f);
        float cg = fminf(fmaxf(gr, 0.f), 255.f);
        float cb = fminf(fmaxf(bl, 0.f), 255.f);
        float ca = fminf(fmaxf(ov.w, 0.f), 255.f);

        __builtin_nontemporal_store(acc, out_x + p[u]);
        __builtin_nontemporal_store((f4){cr, cg, cb, ca}, out_rgba + p[u]);
        __builtin_nontemporal_store(ov, out_ori + p[u]);

        size_t cbase = (size_t)bidx[u] * 3 * HWPIX + rem[u];
        bool ca_pos = (ca > 0.0f);
        __builtin_nontemporal_store(ca_pos ? cr : 255.0f, out_cla + cbase);
        __builtin_nontemporal_store(ca_pos ? cg : 255.0f, out_cla + cbase + HWPIX);
        __builtin_nontemporal_store(ca_pos ? cb : 255.0f, out_cla + cbase + 2 * HWPIX);

        __builtin_nontemporal_store(oa_pos ? ov.x : 255.0f, out_ocla + cbase);
        __builtin_nontemporal_store(oa_pos ? ov.y : 255.0f, out_ocla + cbase + HWPIX);
        __builtin_nontemporal_store(oa_pos ? ov.z : 255.0f, out_ocla + cbase + 2 * HWPIX);
    }
}

extern "C" void kernel_launch(void* const* d_in, const int* in_sizes, int n_in,
                              void* d_out, int out_size, void* d_ws, size_t ws_size,
                              hipStream_t stream) {
    const f4* spatial = (const f4*)d_in[0];
    const f4* wi4     = (const f4*)d_in[1];
    const f4* ori     = (const f4*)d_in[2];
    float* out = (float*)d_out;

    int blocks = (NPIX + SPAN - 1) / SPAN;
    gauss_net_kernel<<<blocks, TPB, 0, stream>>>(spatial, wi4, ori, out);
}

// Round 4
// 229.690 us; speedup vs baseline: 1.6115x; 1.0194x over previous
//
#include <hip/hip_runtime.h>

// Problem constants (from reference)
#define BB 16
#define HH 299
#define WW 299
#define KK 8
#define HWPIX (HH * WW)        // 89401
#define NPIX (BB * HWPIX)      // 1430416
#define PPT 2                  // pixels per thread (16 gathers in flight)
#define TPB 256
#define SPAN (TPB * PPT)

typedef float f4 __attribute__((ext_vector_type(4)));

// r0-r3 established: ~90 us regardless of (waves x per-wave-window) -> the
// divergent gather path is capped per-CU (~45 outstanding L1 misses, each
// random 16B read burns an MSHR + a line fill). Fix under test: bypass L1
// on the gathers with sc0 (agent-scope load, serviced from L2, no L1
// allocation). Table stays L2-resident (no nt on gathers).
__global__ __launch_bounds__(TPB, 4) void gauss_net_kernel(
    const f4* __restrict__ spatial,  // (N_POINTS, 4)
    const f4* __restrict__ wi4,      // (B, 2, H, W, K) viewed as f4
    const f4* __restrict__ ori,      // (B, H, W, 4)
    float* __restrict__ out)
{
    const int tbase = blockIdx.x * SPAN + threadIdx.x;

    // Output layout (flat float offsets)
    f4*    out_x    = (f4*)out;
    f4*    out_rgba = out_x + NPIX;
    float* out_cla  = (float*)(out_rgba + NPIX);
    f4*    out_ori  = (f4*)(out_cla + (size_t)BB * 3 * HWPIX);
    float* out_ocla = (float*)(out_ori + NPIX);

    int  p[PPT], bidx[PPT], rem[PPT];
    bool act[PPT];
    f4   w0[PPT], w1[PPT], i0[PPT], i1[PPT], o[PPT];

    // Phase 1: issue ALL streaming loads (weights, indices, ori) — nt, read-once
#pragma unroll
    for (int u = 0; u < PPT; ++u) {
        p[u]   = tbase + u * TPB;
        act[u] = (p[u] < NPIX);
        int pc = act[u] ? p[u] : 0;
        bidx[u] = pc / HWPIX;
        rem[u]  = pc - bidx[u] * HWPIX;
        size_t wb = ((size_t)(2 * bidx[u]) * HWPIX + rem[u]) * 2;  // f4 units
        size_t ib = wb + (size_t)HWPIX * 2;
        w0[u] = __builtin_nontemporal_load(wi4 + wb);
        w1[u] = __builtin_nontemporal_load(wi4 + wb + 1);
        i0[u] = __builtin_nontemporal_load(wi4 + ib);
        i1[u] = __builtin_nontemporal_load(wi4 + ib + 1);
        o[u]  = __builtin_nontemporal_load(ori + pc);
    }

    // Phase 2: issue ALL gathers with L1 bypass (sc0) — random 16B, L2-resident
    // table. All 16 issued before any consumption.
    f4 g[PPT][KK];
#pragma unroll
    for (int u = 0; u < PPT; ++u) {
        int id[KK] = { (int)i0[u].x, (int)i0[u].y, (int)i0[u].z, (int)i0[u].w,
                       (int)i1[u].x, (int)i1[u].y, (int)i1[u].z, (int)i1[u].w };
#pragma unroll
        for (int k = 0; k < KK; ++k) {
            const f4* ap = spatial + id[k];
            asm volatile("global_load_dwordx4 %0, %1, off sc0"
                         : "=v"(g[u][k]) : "v"(ap));
        }
    }
    // Drain our asm loads, then fence the scheduler so no consumer is hoisted
    // above the waitcnt (rule: inline-asm waitcnt needs a sched_barrier after).
    asm volatile("s_waitcnt vmcnt(0)" ::: "memory");
    __builtin_amdgcn_sched_barrier(0);

    // Phase 3: reduce + epilogue + nt stores (r1-identical math/order)
#pragma unroll
    for (int u = 0; u < PPT; ++u) {
        if (!act[u]) continue;
        float wt[KK] = { w0[u].x, w0[u].y, w0[u].z, w0[u].w,
                         w1[u].x, w1[u].y, w1[u].z, w1[u].w };
        f4 acc = (f4){0.f, 0.f, 0.f, 0.f};
#pragma unroll
        for (int k = 0; k < KK; ++k) acc += g[u][k] * wt[k];

        f4 ov = o[u];
        float alpha = acc.w * (1.0f / 255.0f);
        float r  = fmaf(acc.x, alpha, ov.x);
        float gr = fmaf(acc.y, alpha, ov.y);
        float bl = fmaf(acc.z, alpha, ov.z);
        bool oa_pos = (ov.w > 0.0f);
        if (!oa_pos) { r = 0.f; gr = 0.f; bl = 0.f; }

        float cr = fminf(fmaxf(r,  0.f), 255.f);
        float cg = fminf(fmaxf(gr, 0.f), 255.f);
        float cb = fminf(fmaxf(bl, 0.f), 255.f);
        float ca = fminf(fmaxf(ov.w, 0.f), 255.f);

        __builtin_nontemporal_store(acc, out_x + p[u]);
        __builtin_nontemporal_store((f4){cr, cg, cb, ca}, out_rgba + p[u]);
        __builtin_nontemporal_store(ov, out_ori + p[u]);

        size_t cbase = (size_t)bidx[u] * 3 * HWPIX + rem[u];
        bool ca_pos = (ca > 0.0f);
        __builtin_nontemporal_store(ca_pos ? cr : 255.0f, out_cla + cbase);
        __builtin_nontemporal_store(ca_pos ? cg : 255.0f, out_cla + cbase + HWPIX);
        __builtin_nontemporal_store(ca_pos ? cb : 255.0f, out_cla + cbase + 2 * HWPIX);

        __builtin_nontemporal_store(oa_pos ? ov.x : 255.0f, out_ocla + cbase);
        __builtin_nontemporal_store(oa_pos ? ov.y : 255.0f, out_ocla + cbase + HWPIX);
        __builtin_nontemporal_store(oa_pos ? ov.z : 255.0f, out_ocla + cbase + 2 * HWPIX);
    }
}

extern "C" void kernel_launch(void* const* d_in, const int* in_sizes, int n_in,
                              void* d_out, int out_size, void* d_ws, size_t ws_size,
                              hipStream_t stream) {
    const f4* spatial = (const f4*)d_in[0];
    const f4* wi4     = (const f4*)d_in[1];
    const f4* ori     = (const f4*)d_in[2];
    float* out = (float*)d_out;

    int blocks = (NPIX + SPAN - 1) / SPAN;
    gauss_net_kernel<<<blocks, TPB, 0, stream>>>(spatial, wi4, ori, out);
}